// Round 14
// baseline (80.620 us; speedup 1.0000x reference)
//
#include <hip/hip_runtime.h>
#include <hip/hip_bf16.h>
#include <cstdint>

#define L_SEQ 16384
#define NST   512
#define HDIM  512
#define CH    512   // scan chunks
#define CT    32    // timesteps per chunk (CH*CT = L_SEQ)

typedef __attribute__((ext_vector_type(8))) short short8;
typedef __attribute__((ext_vector_type(4))) float f32x4;

static __device__ __forceinline__ ushort f2bf(float f) {
  union { float f; unsigned int u; } v; v.f = f;
  unsigned int r = v.u + 0x7fffu + ((v.u >> 16) & 1u);
  return (ushort)(r >> 16);
}
static __device__ __forceinline__ float bf2f(ushort u) {
  union { unsigned int u; float f; } v; v.u = ((unsigned int)u) << 16;
  return v.f;
}

static __device__ __forceinline__ void mfma_16x16x32_bf16(f32x4& d, short8 a, short8 b) {
  asm("v_mfma_f32_16x16x32_bf16 %0, %1, %2, %0" : "+v"(d) : "v"(a), "v"(b));
}

static __device__ __forceinline__ void gload_lds16(const ushort* g, ushort* l) {
  __builtin_amdgcn_global_load_lds((__attribute__((address_space(1))) void*)(g),
                                   (__attribute__((address_space(3))) void*)(l),
                                   16, 0, 0);
}

// Channel-interleaved layout: column/row 2c = Re(channel c), 2c+1 = Im(channel c).

// ---------- fused setup: castX + W1 + W2 + lam/lamT ----------
__global__ __launch_bounds__(256) void setup_all(
    const float* __restrict__ st_re, const float* __restrict__ st_im,
    const float* __restrict__ nu_log, const float* __restrict__ theta_log,
    const float* __restrict__ gamma_log,
    const float* __restrict__ B_re, const float* __restrict__ B_im,
    const float* __restrict__ C_re, const float* __restrict__ C_im,
    const float* __restrict__ X,
    float2* __restrict__ lam, float2* __restrict__ lamT,
    ushort* __restrict__ W1, ushort* __restrict__ W2,
    ushort* __restrict__ xb)
{
  int bid = blockIdx.x, tid = threadIdx.x;
  if (bid < 4096) {
    // castX: x (L,512) f32 -> bf16, 8 elems/thread
    size_t i = ((size_t)bid * 256 + tid) * 8;
#pragma unroll
    for (int j = 0; j < 8; j += 4) {
      float4 v = *(const float4*)(X + i + j);
      ushort4 o;
      o.x = f2bf(v.x); o.y = f2bf(v.y); o.z = f2bf(v.z); o.w = f2bf(v.w);
      *(ushort4*)(xb + i + j) = o;
    }
  } else if (bid < 5120) {
    // W1 rows interleaved: row 2n = Re(B*e^{ig}) ch n, row 2n+1 = Im
    int idx = (bid - 4096) * 256 + tid;   // n*512 + h
    int n = idx >> 9, h = idx & 511;
    float g = gamma_log[n];
    float sg, cg; sincosf(g, &sg, &cg);
    float br = B_re[idx], bi = B_im[idx];
    W1[(size_t)(2 * n) * 512 + h]     = f2bf(br * cg - bi * sg);
    W1[(size_t)(2 * n + 1) * 512 + h] = f2bf(br * sg + bi * cg);
  } else if (bid < 6144) {
    // W2 k-dim interleaved: W2[h][2n] = C_re, W2[h][2n+1] = -C_im
    int idx = (bid - 5120) * 256 + tid;   // hh*512 + n
    int hh = idx >> 9, n = idx & 511;
    W2[(size_t)hh * 1024 + 2 * n]     = f2bf(C_re[idx]);
    W2[(size_t)hh * 1024 + 2 * n + 1] = f2bf(-C_im[idx]);
  } else {
    // prep: a = Lambda*state, aT = a^CT
    int n = (bid - 6144) * 256 + tid;
    float nu  = expf(nu_log[n]);
    float th  = expf(theta_log[n]);
    float mag = expf(-nu);
    float sth, cth; sincosf(th, &sth, &cth);
    float lr = mag * cth, li = mag * sth;
    float sr = st_re[n], si = st_im[n];
    float ar = lr * sr - li * si;
    float ai = lr * si + li * sr;
    lam[n] = make_float2(ar, ai);
    float pr = ar, pi = ai;
#pragma unroll
    for (int i = 0; i < 5; ++i) {   // a^(2^5) = a^CT, CT=32
      float nr = pr * pr - pi * pi;
      float ni = 2.f * pr * pi;
      pr = nr; pi = ni;
    }
    lamT[n] = make_float2(pr, pi);
  }
}

// ---------- pipelined GEMM: C[m,j] = sum_k A[m,k]*B[j,k] ----------
// 3-slot LDS ring (stage 2 tiles ahead), BK=32, counted vmcnt (LPT in steady
// state, never 0 until tail), ONE raw s_barrier per K-step, XOR-swizzled LDS
// (inverse-swizzled global source, rule 21). 72KB LDS -> 2 blocks/CU capacity.
// Fragments are read AFTER the barrier that publishes their slot — vmcnt is
// per-wave, so cross-wave LDS staging is only visible post-barrier (R13 lesson).
// stage() is issued first in each step (earliest global-load issue; writes a
// different ring slot than the one being read: kt+2 != kt mod 3).
// EPI==0 (gemm1): bf16 C; fused per-chunk carry scan reads the C-tile from
//                 LDS (epilogue deposits it into the dead ring buffer).
// EPI==1 (gemm2): f32 C with +D*x epilogue from bf16 xb.
template <int BM, int BN, int WMW, int WNW, int EPI>
__global__ __launch_bounds__(WMW * WNW * 64, 4)
void gemm_p(const ushort* __restrict__ A, const ushort* __restrict__ Bm,
            ushort* __restrict__ Cb, float* __restrict__ Cf,
            const float* __restrict__ Dv, const ushort* __restrict__ Xb,
            const float2* __restrict__ lam, float2* __restrict__ carry,
            int M, int Ncols, int K)
{
  constexpr int THREADS = WMW * WNW * 64;
  constexpr int FM = BM / (WMW * 16);
  constexpr int FN = BN / (WNW * 16);
  constexpr int SLOT = (BM + BN) * 32;            // ushorts per k-tile (A then B)
  constexpr int LPT  = (BM + BN) * 4 / THREADS;   // 16B granules per thread
  static_assert(LPT == 3 || LPT == 4, "vmcnt immediates cover LPT 3/4");
  static_assert(EPI != 0 || 3 * SLOT >= BM * BN, "ring must hold C-tile for LDS carries");
  __shared__ __align__(16) ushort lds[3 * SLOT];

  const int t = threadIdx.x, lane = t & 63, w = t >> 6;
  const int wr = w / WNW, wc = w % WNW;
  const int m0 = blockIdx.x * BM, n0 = blockIdx.y * BN;
  const int rr = lane & 15, kk = (lane >> 4) * 8;
  const int swzu = ((rr >> 1) & 3) << 3;     // read-side XOR, ushort units
  const int NK = K / 32;

  f32x4 acc[FM][FN];
#pragma unroll
  for (int i = 0; i < FM; ++i)
#pragma unroll
    for (int j = 0; j < FN; ++j) { f32x4 z = {0.f, 0.f, 0.f, 0.f}; acc[i][j] = z; }

  auto stage = [&](int kt) {
    int k0 = kt * 32;
    ushort* base = lds + (kt % 3) * SLOT;
#pragma unroll
    for (int j = 0; j < LPT; ++j) {
      int d = j * THREADS + t;                 // dest granule (linear, wave-contiguous)
      const ushort* g;
      if (d < BM * 4) {
        int row = d >> 2;
        int sl  = (d & 3) ^ ((row >> 1) & 3);  // inverse swizzle (involution)
        g = A + (size_t)(m0 + row) * K + k0 + sl * 8;
      } else {
        int dd = d - BM * 4;
        int row = dd >> 2;
        int sl  = (dd & 3) ^ ((row >> 1) & 3);
        g = Bm + (size_t)(n0 + row) * K + k0 + sl * 8;
      }
      gload_lds16(g, base + d * 8);
    }
  };

  // prologue: stage tiles 0,1; wait tile0 resident (tile1 may stay in flight)
  stage(0); stage(1);
  if constexpr (LPT == 4) asm volatile("s_waitcnt vmcnt(4)" ::: "memory");
  else                    asm volatile("s_waitcnt vmcnt(3)" ::: "memory");
  asm volatile("s_barrier" ::: "memory");

  for (int kt = 0; kt < NK; ++kt) {
    if (kt + 2 < NK) stage(kt + 2);            // earliest issue; slot != kt%3
    const ushort* As = lds + (kt % 3) * SLOT;
    const ushort* Bs = As + BM * 32;
    short8 af[FM], bb[FN];
#pragma unroll
    for (int mi = 0; mi < FM; ++mi)
      af[mi] = *(const short8*)(As + (wr * FM * 16 + mi * 16 + rr) * 32 + (kk ^ swzu));
#pragma unroll
    for (int ni = 0; ni < FN; ++ni)
      bb[ni] = *(const short8*)(Bs + (wc * FN * 16 + ni * 16 + rr) * 32 + (kk ^ swzu));
    __builtin_amdgcn_s_setprio(1);
#pragma unroll
    for (int mi = 0; mi < FM; ++mi)
#pragma unroll
      for (int ni = 0; ni < FN; ++ni)
        mfma_16x16x32_bf16(acc[mi][ni], af[mi], bb[ni]);
    __builtin_amdgcn_s_setprio(0);
    // counted vmcnt: next tile must be resident; kt+2's stage may stay in flight
    if (kt <= NK - 3) {
      if constexpr (LPT == 4) asm volatile("s_waitcnt vmcnt(4)" ::: "memory");
      else                    asm volatile("s_waitcnt vmcnt(3)" ::: "memory");
    } else {
      asm volatile("s_waitcnt vmcnt(0)" ::: "memory");
    }
    asm volatile("s_barrier" ::: "memory");
  }

  // epilogue: C/D layout col = lane&15, row = (lane>>4)*4 + reg
  const int crow = (lane >> 4) * 4, ccol = lane & 15;
#pragma unroll
  for (int mi = 0; mi < FM; ++mi) {
#pragma unroll
    for (int ni = 0; ni < FN; ++ni) {
      int col = n0 + wc * FN * 16 + ni * 16 + ccol;
#pragma unroll
      for (int r = 0; r < 4; ++r) {
        int row = m0 + wr * FM * 16 + mi * 16 + crow + r;
        float v = acc[mi][ni][r];
        size_t idx = (size_t)row * Ncols + col;
        if constexpr (EPI == 0) {
          ushort bv = f2bf(v);
          Cb[idx] = bv;                               // global (for scanB)
          lds[(row - m0) * BN + (col - n0)] = bv;     // LDS copy (for carries)
        } else {
          Cf[idx] = v + Dv[col] * bf2f(Xb[idx]);
        }
      }
    }
  }

  if constexpr (EPI == 0) {
    // fused scanA: per-chunk carries from the LDS C-tile (no global round-trip).
    // Block owns BM/32=4 chunks x BN/2=128 channels = 512 tasks = THREADS.
    __syncthreads();
    {
      int c  = t >> 7;                     // chunk within block (0..3)
      int ch = t & 127;                    // channel within block
      float2 a = lam[(n0 >> 1) + ch];
      float cr = 0.f, ci = 0.f;
      const ushort* p = lds + (c * 32) * BN + 2 * ch;
#pragma unroll 8
      for (int r = 0; r < 32; ++r) {
        ushort2 v = *(const ushort2*)(p + r * BN);
        float br = bf2f(v.x), bi = bf2f(v.y);
        float nr = a.x * cr - a.y * ci + br;
        float ni = a.x * ci + a.y * cr + bi;
        cr = nr; ci = ni;
      }
      carry[(size_t)((n0 >> 1) + ch) * CH + (m0 >> 5) + c] = make_float2(cr, ci);
    }
  }
}

// ---------- scan pass C: Kogge-Stone scan over chunk carries, one block/channel ----------
__global__ __launch_bounds__(CH) void scanC(const float2* __restrict__ carry,
                                            const float2* __restrict__ lamT,
                                            float2* __restrict__ prefix)
{
  int n = blockIdx.x;
  int c = threadIdx.x;
  __shared__ float2 buf[CH];
  float2 aT = lamT[n];
  float2 v = carry[(size_t)n * CH + c];
  buf[c] = v;
  __syncthreads();
  float mr = aT.x, mi = aT.y;
#pragma unroll
  for (int s = 1; s < CH; s <<= 1) {
    float2 o = make_float2(0.f, 0.f);
    if (c >= s) o = buf[c - s];
    __syncthreads();
    v.x += mr * o.x - mi * o.y;
    v.y += mr * o.y + mi * o.x;
    buf[c] = v;
    __syncthreads();
    float nmr = mr * mr - mi * mi;
    float nmi = 2.f * mr * mi;
    mr = nmr; mi = nmi;
  }
  float2 p = (c == 0) ? make_float2(0.f, 0.f) : buf[c - 1];
  prefix[(size_t)n * CH + c] = p;
}

// ---------- scan pass B: full recurrence, overwrite Bu with h (bf16) ----------
// XCD-affinity relabel (bijective swap of low 3-bit fields).
__global__ __launch_bounds__(256) void scanB(ushort* __restrict__ Bu,
                                             const float2* __restrict__ lam,
                                             const float2* __restrict__ prefix)
{
  int b = blockIdx.x;
  int c = (b & ~63) | ((b & 7) << 3) | ((b >> 3) & 7);
  int q = threadIdx.x;
  float2 a0 = lam[2 * q], a1 = lam[2 * q + 1];
  float2 g0 = prefix[(size_t)(2 * q) * CH + c];
  float2 g1 = prefix[(size_t)(2 * q + 1) * CH + c];
  float hr0 = g0.x, hi0 = g0.y, hr1 = g1.x, hi1 = g1.y;
  ushort* base = Bu + (size_t)c * CT * 1024 + 4 * q;
#pragma unroll 4
  for (int tt = 0; tt < CT; ++tt) {
    ushort4 v = *(const ushort4*)(base + tt * 1024);
    float nr0 = a0.x * hr0 - a0.y * hi0 + bf2f(v.x);
    float ni0 = a0.x * hi0 + a0.y * hr0 + bf2f(v.y);
    hr0 = nr0; hi0 = ni0;
    float nr1 = a1.x * hr1 - a1.y * hi1 + bf2f(v.z);
    float ni1 = a1.x * hi1 + a1.y * hr1 + bf2f(v.w);
    hr1 = nr1; hi1 = ni1;
    ushort4 o;
    o.x = f2bf(hr0); o.y = f2bf(hi0);
    o.z = f2bf(hr1); o.w = f2bf(hi1);
    *(ushort4*)(base + tt * 1024) = o;
  }
}

extern "C" void kernel_launch(void* const* d_in, const int* in_sizes, int n_in,
                              void* d_out, int out_size, void* d_ws, size_t ws_size,
                              hipStream_t stream)
{
  const float* x         = (const float*)d_in[0];
  const float* state_re  = (const float*)d_in[1];
  const float* state_im  = (const float*)d_in[2];
  const float* nu_log    = (const float*)d_in[3];
  const float* theta_log = (const float*)d_in[4];
  const float* gamma_log = (const float*)d_in[5];
  const float* B_re      = (const float*)d_in[6];
  const float* B_im      = (const float*)d_in[7];
  const float* C_re      = (const float*)d_in[8];
  const float* C_im      = (const float*)d_in[9];
  const float* Dv        = (const float*)d_in[10];
  float* y = (float*)d_out;

  char* ws = (char*)d_ws;
  size_t off = 0;
  float2* lam    = (float2*)(ws + off); off += 4096;
  float2* lamT   = (float2*)(ws + off); off += 4096;
  float2* carry  = (float2*)(ws + off); off += (size_t)CH * NST * sizeof(float2);
  float2* prefix = (float2*)(ws + off); off += (size_t)CH * NST * sizeof(float2);
  ushort* W1 = (ushort*)(ws + off); off += (size_t)2 * NST * HDIM * sizeof(ushort);
  ushort* W2 = (ushort*)(ws + off); off += (size_t)HDIM * 2 * NST * sizeof(ushort);
  ushort* xb = (ushort*)(ws + off); off += (size_t)L_SEQ * HDIM * sizeof(ushort);
  ushort* Bu = (ushort*)(ws + off); off += (size_t)L_SEQ * 2 * NST * sizeof(ushort);

  setup_all<<<6146, 256, 0, stream>>>(state_re, state_im, nu_log, theta_log,
                                      gamma_log, B_re, B_im, C_re, C_im, x,
                                      lam, lamT, W1, W2, xb);

  // Bu = x @ W1^T -> (L, 1024) bf16, interleaved cols; fused chunk-carry scan
  // 128x256 tile, 8 waves, 72KB LDS, grid 128x4=512 -> 2 blocks/CU
  gemm_p<128, 256, 2, 4, 0><<<dim3(L_SEQ / 128, (2 * NST) / 256), 512, 0, stream>>>(
      xb, W1, Bu, nullptr, nullptr, nullptr, lam, carry, L_SEQ, 2 * NST, HDIM);

  scanC<<<NST, CH, 0, stream>>>(carry, lamT, prefix);
  scanB<<<CH, 256, 0, stream>>>(Bu, lam, prefix);

  // y = h @ W2^T + D*x -> (L, 512) f32 ; 128x256 tile, 8 waves, 72KB LDS,
  // grid 128x2=256 (same template shape as gemm1; halves B re-reads)
  gemm_p<128, 256, 2, 4, 1><<<dim3(L_SEQ / 128, HDIM / 256), 512, 0, stream>>>(
      Bu, W2, nullptr, y, Dv, xb, nullptr, nullptr, L_SEQ, HDIM, 2 * NST);
}

// Round 15
// 78.586 us; speedup vs baseline: 1.0259x; 1.0259x over previous
//
#include <hip/hip_runtime.h>
#include <hip/hip_bf16.h>
#include <cstdint>

#define L_SEQ 16384
#define NST   512
#define HDIM  512
#define CH    512   // scan chunks
#define CT    32    // timesteps per chunk (CH*CT = L_SEQ)

typedef __attribute__((ext_vector_type(8))) short short8;
typedef __attribute__((ext_vector_type(4))) float f32x4;

static __device__ __forceinline__ ushort f2bf(float f) {
  union { float f; unsigned int u; } v; v.f = f;
  unsigned int r = v.u + 0x7fffu + ((v.u >> 16) & 1u);
  return (ushort)(r >> 16);
}
static __device__ __forceinline__ float bf2f(ushort u) {
  union { unsigned int u; float f; } v; v.u = ((unsigned int)u) << 16;
  return v.f;
}

static __device__ __forceinline__ void mfma_16x16x32_bf16(f32x4& d, short8 a, short8 b) {
  asm("v_mfma_f32_16x16x32_bf16 %0, %1, %2, %0" : "+v"(d) : "v"(a), "v"(b));
}

static __device__ __forceinline__ void gload_lds16(const ushort* g, ushort* l) {
  __builtin_amdgcn_global_load_lds((__attribute__((address_space(1))) void*)(g),
                                   (__attribute__((address_space(3))) void*)(l),
                                   16, 0, 0);
}

// Channel-interleaved layout: column/row 2c = Re(channel c), 2c+1 = Im(channel c).

// ---------- fused setup: castX + W1 + W2 + lam/lamT ----------
__global__ __launch_bounds__(256) void setup_all(
    const float* __restrict__ st_re, const float* __restrict__ st_im,
    const float* __restrict__ nu_log, const float* __restrict__ theta_log,
    const float* __restrict__ gamma_log,
    const float* __restrict__ B_re, const float* __restrict__ B_im,
    const float* __restrict__ C_re, const float* __restrict__ C_im,
    const float* __restrict__ X,
    float2* __restrict__ lam, float2* __restrict__ lamT,
    ushort* __restrict__ W1, ushort* __restrict__ W2,
    ushort* __restrict__ xb)
{
  int bid = blockIdx.x, tid = threadIdx.x;
  if (bid < 4096) {
    // castX: x (L,512) f32 -> bf16, 8 elems/thread
    size_t i = ((size_t)bid * 256 + tid) * 8;
#pragma unroll
    for (int j = 0; j < 8; j += 4) {
      float4 v = *(const float4*)(X + i + j);
      ushort4 o;
      o.x = f2bf(v.x); o.y = f2bf(v.y); o.z = f2bf(v.z); o.w = f2bf(v.w);
      *(ushort4*)(xb + i + j) = o;
    }
  } else if (bid < 5120) {
    // W1 rows interleaved: row 2n = Re(B*e^{ig}) ch n, row 2n+1 = Im
    int idx = (bid - 4096) * 256 + tid;   // n*512 + h
    int n = idx >> 9, h = idx & 511;
    float g = gamma_log[n];
    float sg, cg; sincosf(g, &sg, &cg);
    float br = B_re[idx], bi = B_im[idx];
    W1[(size_t)(2 * n) * 512 + h]     = f2bf(br * cg - bi * sg);
    W1[(size_t)(2 * n + 1) * 512 + h] = f2bf(br * sg + bi * cg);
  } else if (bid < 6144) {
    // W2 k-dim interleaved: W2[h][2n] = C_re, W2[h][2n+1] = -C_im
    int idx = (bid - 5120) * 256 + tid;   // hh*512 + n
    int hh = idx >> 9, n = idx & 511;
    W2[(size_t)hh * 1024 + 2 * n]     = f2bf(C_re[idx]);
    W2[(size_t)hh * 1024 + 2 * n + 1] = f2bf(-C_im[idx]);
  } else {
    // prep: a = Lambda*state, aT = a^CT
    int n = (bid - 6144) * 256 + tid;
    float nu  = expf(nu_log[n]);
    float th  = expf(theta_log[n]);
    float mag = expf(-nu);
    float sth, cth; sincosf(th, &sth, &cth);
    float lr = mag * cth, li = mag * sth;
    float sr = st_re[n], si = st_im[n];
    float ar = lr * sr - li * si;
    float ai = lr * si + li * sr;
    lam[n] = make_float2(ar, ai);
    float pr = ar, pi = ai;
#pragma unroll
    for (int i = 0; i < 5; ++i) {   // a^(2^5) = a^CT, CT=32
      float nr = pr * pr - pi * pi;
      float ni = 2.f * pr * pi;
      pr = nr; pi = ni;
    }
    lamT[n] = make_float2(pr, pi);
  }
}

// ---------- pipelined GEMM: C[m,j] = sum_k A[m,k]*B[j,k] ----------
// 3-slot LDS ring (stage 2 tiles ahead), BK=32, counted vmcnt (LPT in steady
// state, never 0 until tail), ONE raw s_barrier per K-step, XOR-swizzled LDS
// (inverse-swizzled global source, rule 21). 72KB LDS -> 2 blocks/CU capacity.
// Fragments are read AFTER the barrier that publishes their slot — vmcnt is
// per-wave, so cross-wave LDS staging is only visible post-barrier (R13 lesson).
// stage() issued after the fragment reads (R14 A/B: stage-first cost ~1.5us).
// EPI==0 (gemm1): bf16 C; fused per-chunk carry scan reads the C-tile from
//                 LDS (epilogue deposits it into the dead ring buffer).
// EPI==1 (gemm2): f32 C with +D*x epilogue from bf16 xb.
template <int BM, int BN, int WMW, int WNW, int EPI>
__global__ __launch_bounds__(WMW * WNW * 64, 4)
void gemm_p(const ushort* __restrict__ A, const ushort* __restrict__ Bm,
            ushort* __restrict__ Cb, float* __restrict__ Cf,
            const float* __restrict__ Dv, const ushort* __restrict__ Xb,
            const float2* __restrict__ lam, float2* __restrict__ carry,
            int M, int Ncols, int K)
{
  constexpr int THREADS = WMW * WNW * 64;
  constexpr int FM = BM / (WMW * 16);
  constexpr int FN = BN / (WNW * 16);
  constexpr int SLOT = (BM + BN) * 32;            // ushorts per k-tile (A then B)
  constexpr int LPT  = (BM + BN) * 4 / THREADS;   // 16B granules per thread
  static_assert(LPT == 3 || LPT == 4, "vmcnt immediates cover LPT 3/4");
  static_assert(EPI != 0 || 3 * SLOT >= BM * BN, "ring must hold C-tile for LDS carries");
  __shared__ __align__(16) ushort lds[3 * SLOT];

  const int t = threadIdx.x, lane = t & 63, w = t >> 6;
  const int wr = w / WNW, wc = w % WNW;
  const int m0 = blockIdx.x * BM, n0 = blockIdx.y * BN;
  const int rr = lane & 15, kk = (lane >> 4) * 8;
  const int swzu = ((rr >> 1) & 3) << 3;     // read-side XOR, ushort units
  const int NK = K / 32;

  f32x4 acc[FM][FN];
#pragma unroll
  for (int i = 0; i < FM; ++i)
#pragma unroll
    for (int j = 0; j < FN; ++j) { f32x4 z = {0.f, 0.f, 0.f, 0.f}; acc[i][j] = z; }

  auto stage = [&](int kt) {
    int k0 = kt * 32;
    ushort* base = lds + (kt % 3) * SLOT;
#pragma unroll
    for (int j = 0; j < LPT; ++j) {
      int d = j * THREADS + t;                 // dest granule (linear, wave-contiguous)
      const ushort* g;
      if (d < BM * 4) {
        int row = d >> 2;
        int sl  = (d & 3) ^ ((row >> 1) & 3);  // inverse swizzle (involution)
        g = A + (size_t)(m0 + row) * K + k0 + sl * 8;
      } else {
        int dd = d - BM * 4;
        int row = dd >> 2;
        int sl  = (dd & 3) ^ ((row >> 1) & 3);
        g = Bm + (size_t)(n0 + row) * K + k0 + sl * 8;
      }
      gload_lds16(g, base + d * 8);
    }
  };

  // prologue: stage tiles 0,1; wait tile0 resident (tile1 may stay in flight)
  stage(0); stage(1);
  if constexpr (LPT == 4) asm volatile("s_waitcnt vmcnt(4)" ::: "memory");
  else                    asm volatile("s_waitcnt vmcnt(3)" ::: "memory");
  asm volatile("s_barrier" ::: "memory");

  for (int kt = 0; kt < NK; ++kt) {
    const ushort* As = lds + (kt % 3) * SLOT;
    const ushort* Bs = As + BM * 32;
    short8 af[FM], bb[FN];
#pragma unroll
    for (int mi = 0; mi < FM; ++mi)
      af[mi] = *(const short8*)(As + (wr * FM * 16 + mi * 16 + rr) * 32 + (kk ^ swzu));
#pragma unroll
    for (int ni = 0; ni < FN; ++ni)
      bb[ni] = *(const short8*)(Bs + (wc * FN * 16 + ni * 16 + rr) * 32 + (kk ^ swzu));
    if (kt + 2 < NK) stage(kt + 2);
    __builtin_amdgcn_s_setprio(1);
#pragma unroll
    for (int mi = 0; mi < FM; ++mi)
#pragma unroll
      for (int ni = 0; ni < FN; ++ni)
        mfma_16x16x32_bf16(acc[mi][ni], af[mi], bb[ni]);
    __builtin_amdgcn_s_setprio(0);
    // counted vmcnt: next tile must be resident; kt+2's stage may stay in flight
    if (kt <= NK - 3) {
      if constexpr (LPT == 4) asm volatile("s_waitcnt vmcnt(4)" ::: "memory");
      else                    asm volatile("s_waitcnt vmcnt(3)" ::: "memory");
    } else {
      asm volatile("s_waitcnt vmcnt(0)" ::: "memory");
    }
    asm volatile("s_barrier" ::: "memory");
  }

  // epilogue: C/D layout col = lane&15, row = (lane>>4)*4 + reg
  const int crow = (lane >> 4) * 4, ccol = lane & 15;
#pragma unroll
  for (int mi = 0; mi < FM; ++mi) {
#pragma unroll
    for (int ni = 0; ni < FN; ++ni) {
      int col = n0 + wc * FN * 16 + ni * 16 + ccol;
#pragma unroll
      for (int r = 0; r < 4; ++r) {
        int row = m0 + wr * FM * 16 + mi * 16 + crow + r;
        float v = acc[mi][ni][r];
        size_t idx = (size_t)row * Ncols + col;
        if constexpr (EPI == 0) {
          ushort bv = f2bf(v);
          Cb[idx] = bv;                               // global (for scanB)
          lds[(row - m0) * BN + (col - n0)] = bv;     // LDS copy (for carries)
        } else {
          Cf[idx] = v + Dv[col] * bf2f(Xb[idx]);
        }
      }
    }
  }

  if constexpr (EPI == 0) {
    // fused scanA: per-chunk carries from the LDS C-tile (no global round-trip).
    // Block owns BM/32=4 chunks x BN/2=128 channels = 512 tasks = THREADS.
    __syncthreads();
    {
      int c  = t >> 7;                     // chunk within block (0..3)
      int ch = t & 127;                    // channel within block
      float2 a = lam[(n0 >> 1) + ch];
      float cr = 0.f, ci = 0.f;
      const ushort* p = lds + (c * 32) * BN + 2 * ch;
#pragma unroll 8
      for (int r = 0; r < 32; ++r) {
        ushort2 v = *(const ushort2*)(p + r * BN);
        float br = bf2f(v.x), bi = bf2f(v.y);
        float nr = a.x * cr - a.y * ci + br;
        float ni = a.x * ci + a.y * cr + bi;
        cr = nr; ci = ni;
      }
      carry[(size_t)((n0 >> 1) + ch) * CH + (m0 >> 5) + c] = make_float2(cr, ci);
    }
  }
}

// ---------- scan pass C: Kogge-Stone scan over chunk carries, one block/channel ----------
__global__ __launch_bounds__(CH) void scanC(const float2* __restrict__ carry,
                                            const float2* __restrict__ lamT,
                                            float2* __restrict__ prefix)
{
  int n = blockIdx.x;
  int c = threadIdx.x;
  __shared__ float2 buf[CH];
  float2 aT = lamT[n];
  float2 v = carry[(size_t)n * CH + c];
  buf[c] = v;
  __syncthreads();
  float mr = aT.x, mi = aT.y;
#pragma unroll
  for (int s = 1; s < CH; s <<= 1) {
    float2 o = make_float2(0.f, 0.f);
    if (c >= s) o = buf[c - s];
    __syncthreads();
    v.x += mr * o.x - mi * o.y;
    v.y += mr * o.y + mi * o.x;
    buf[c] = v;
    __syncthreads();
    float nmr = mr * mr - mi * mi;
    float nmi = 2.f * mr * mi;
    mr = nmr; mi = nmi;
  }
  float2 p = (c == 0) ? make_float2(0.f, 0.f) : buf[c - 1];
  prefix[(size_t)n * CH + c] = p;
}

// ---------- scan pass B: full recurrence, overwrite Bu with h (bf16) ----------
// XCD-affinity relabel (bijective swap of low 3-bit fields).
__global__ __launch_bounds__(256) void scanB(ushort* __restrict__ Bu,
                                             const float2* __restrict__ lam,
                                             const float2* __restrict__ prefix)
{
  int b = blockIdx.x;
  int c = (b & ~63) | ((b & 7) << 3) | ((b >> 3) & 7);
  int q = threadIdx.x;
  float2 a0 = lam[2 * q], a1 = lam[2 * q + 1];
  float2 g0 = prefix[(size_t)(2 * q) * CH + c];
  float2 g1 = prefix[(size_t)(2 * q + 1) * CH + c];
  float hr0 = g0.x, hi0 = g0.y, hr1 = g1.x, hi1 = g1.y;
  ushort* base = Bu + (size_t)c * CT * 1024 + 4 * q;
#pragma unroll 4
  for (int tt = 0; tt < CT; ++tt) {
    ushort4 v = *(const ushort4*)(base + tt * 1024);
    float nr0 = a0.x * hr0 - a0.y * hi0 + bf2f(v.x);
    float ni0 = a0.x * hi0 + a0.y * hr0 + bf2f(v.y);
    hr0 = nr0; hi0 = ni0;
    float nr1 = a1.x * hr1 - a1.y * hi1 + bf2f(v.z);
    float ni1 = a1.x * hi1 + a1.y * hr1 + bf2f(v.w);
    hr1 = nr1; hi1 = ni1;
    ushort4 o;
    o.x = f2bf(hr0); o.y = f2bf(hi0);
    o.z = f2bf(hr1); o.w = f2bf(hi1);
    *(ushort4*)(base + tt * 1024) = o;
  }
}

extern "C" void kernel_launch(void* const* d_in, const int* in_sizes, int n_in,
                              void* d_out, int out_size, void* d_ws, size_t ws_size,
                              hipStream_t stream)
{
  const float* x         = (const float*)d_in[0];
  const float* state_re  = (const float*)d_in[1];
  const float* state_im  = (const float*)d_in[2];
  const float* nu_log    = (const float*)d_in[3];
  const float* theta_log = (const float*)d_in[4];
  const float* gamma_log = (const float*)d_in[5];
  const float* B_re      = (const float*)d_in[6];
  const float* B_im      = (const float*)d_in[7];
  const float* C_re      = (const float*)d_in[8];
  const float* C_im      = (const float*)d_in[9];
  const float* Dv        = (const float*)d_in[10];
  float* y = (float*)d_out;

  char* ws = (char*)d_ws;
  size_t off = 0;
  float2* lam    = (float2*)(ws + off); off += 4096;
  float2* lamT   = (float2*)(ws + off); off += 4096;
  float2* carry  = (float2*)(ws + off); off += (size_t)CH * NST * sizeof(float2);
  float2* prefix = (float2*)(ws + off); off += (size_t)CH * NST * sizeof(float2);
  ushort* W1 = (ushort*)(ws + off); off += (size_t)2 * NST * HDIM * sizeof(ushort);
  ushort* W2 = (ushort*)(ws + off); off += (size_t)HDIM * 2 * NST * sizeof(ushort);
  ushort* xb = (ushort*)(ws + off); off += (size_t)L_SEQ * HDIM * sizeof(ushort);
  ushort* Bu = (ushort*)(ws + off); off += (size_t)L_SEQ * 2 * NST * sizeof(ushort);

  setup_all<<<6146, 256, 0, stream>>>(state_re, state_im, nu_log, theta_log,
                                      gamma_log, B_re, B_im, C_re, C_im, x,
                                      lam, lamT, W1, W2, xb);

  // Bu = x @ W1^T -> (L, 1024) bf16, interleaved cols; fused chunk-carry scan
  // 128x256 tile, 8 waves, 72KB LDS, grid 128x4=512 -> 2 blocks/CU
  gemm_p<128, 256, 2, 4, 0><<<dim3(L_SEQ / 128, (2 * NST) / 256), 512, 0, stream>>>(
      xb, W1, Bu, nullptr, nullptr, nullptr, lam, carry, L_SEQ, 2 * NST, HDIM);

  scanC<<<NST, CH, 0, stream>>>(carry, lamT, prefix);
  scanB<<<CH, 256, 0, stream>>>(Bu, lam, prefix);

  // y = h @ W2^T + D*x -> (L, 512) f32 ; 128x256 tile, 8 waves, 72KB LDS,
  // grid 128x2=256 (same template shape as gemm1; halves B re-reads)
  gemm_p<128, 256, 2, 4, 1><<<dim3(L_SEQ / 128, HDIM / 256), 512, 0, stream>>>(
      Bu, W2, nullptr, y, Dv, xb, nullptr, nullptr, L_SEQ, HDIM, 2 * NST);
}